// Round 1
// 131.404 us; speedup vs baseline: 1.0008x; 1.0008x over previous
//
#include <hip/hip_runtime.h>
#include <math.h>

#define BATCH 2
#define CIN   256
#define COUT  256
#define COFF  256
#define HWPIX 4096
#define CKTOT 2304
#define VSTR  40            // V row stride in shorts (80 B)
#define PH    66            // padded feat spatial dim
#define PHW   4356          // 66*66
#define NKG   12            // conv_om K-split

typedef __attribute__((ext_vector_type(8))) short short8;
typedef __attribute__((ext_vector_type(8))) unsigned short ushort8;
typedef __attribute__((ext_vector_type(4))) float float4v;

__device__ __forceinline__ unsigned short f2bf(float f) {
    unsigned u = __float_as_uint(f);
    unsigned r = (u + 0x7FFFu + ((u >> 16) & 1u)) >> 16;   // RNE
    return (unsigned short)r;
}
__device__ __forceinline__ float bf2f(unsigned short h) {
    return __uint_as_float(((unsigned)h) << 16);
}

// ---------------------------------------------------------------------------
// prep: ONE kernel, blockIdx regions:
//   [0,2048)      x -> xTh (NHWC, bf16)
//   [2048,4096)   feat -> fh (NHWC, zero-padded 66x66, bf16)
//   [4096,6400)   wpack   (w_dcn -> whi, bf16, A-frag layout)
//   [6400,6688)   wpack_om(w_offset_mask -> wohi, M=32 padded, bf16)
//   [6688,7208)   zero fh borders (both batches)
//   [7208,9256)   zero out (float4) — needed by dcn's atomic epilogue
// ---------------------------------------------------------------------------
__global__ __launch_bounds__(256) void prep_kernel(
    const float* __restrict__ x, const float* __restrict__ feat,
    const float* __restrict__ wdcn, const float* __restrict__ wom,
    unsigned short* __restrict__ xTh,
    unsigned short* __restrict__ fh,
    unsigned short* __restrict__ whi,
    unsigned short* __restrict__ wohi,
    float* __restrict__ out)
{
    const int bid = blockIdx.x;
    const int tid = threadIdx.x;

    if (bid < 4096) {
        const bool isx = bid < 2048;
        const int lb = isx ? bid : bid - 2048;
        const int b  = lb >> 10;
        const int r  = lb & 1023;
        const int pt = r >> 3;       // 128 px tiles of 32
        const int ct = r & 7;        // 8 ch tiles of 32
        __shared__ float t[32][33];
        const int tx = tid & 31, ty = tid >> 5;
        const float* src = isx ? x : feat;
        const float* sb = src + ((size_t)b * 256 + ct * 32) * HWPIX + pt * 32;
#pragma unroll
        for (int i = ty; i < 32; i += 8)
            t[i][tx] = sb[(size_t)i * HWPIX + tx];
        __syncthreads();
        if (isx) {
            unsigned short* ob = xTh + ((size_t)b * HWPIX + pt * 32) * 256 + ct * 32;
#pragma unroll
            for (int i = ty; i < 32; i += 8)
                ob[(size_t)i * 256 + tx] = f2bf(t[tx][i]);
        } else {
#pragma unroll
            for (int i = ty; i < 32; i += 8) {
                int p = pt * 32 + i;
                int row = (p >> 6) + 1, col = (p & 63) + 1;
                fh[((size_t)b * PHW + row * PH + col) * 256 + ct * 32 + tx]
                    = f2bf(t[tx][i]);
            }
        }
    } else if (bid < 6400) {
        int gid = (bid - 4096) * 256 + tid;    // 0..589823
        int cc  = gid & 31;
        int co  = (gid >> 5) & 255;
        int kcb = gid >> 13;
        int k   = kcb >> 3;
        int cb  = kcb & 7;
        float w = wdcn[((size_t)co * 256 + cb * 32 + cc) * 9 + k];
        whi[gid] = f2bf(w);
    } else if (bid < 6688) {
        int gid = (bid - 6400) * 256 + tid;    // 0..73727
        int cc  = gid & 31;
        int co  = (gid >> 5) & 31;
        int kcb = gid >> 10;
        int k   = kcb >> 3;
        int cb  = kcb & 7;
        float w = 0.0f;
        if (co < 27) w = wom[(size_t)co * CKTOT + (cb * 32 + cc) * 9 + k];
        wohi[gid] = f2bf(w);
    } else if (bid < 7208) {
        int idx = (bid - 6688) * 256 + tid;    // < 133120 = 2*260*256 exactly
        int b = idx / 66560;
        int r = idx - b * 66560;
        int pidx = r >> 8;                     // 0..259 border cells
        int c = r & 255;
        int row, col;
        if (pidx < 66)       { row = 0;           col = pidx; }
        else if (pidx < 132) { row = 65;          col = pidx - 66; }
        else if (pidx < 196) { row = pidx - 131;  col = 0; }
        else                 { row = pidx - 195;  col = 65; }
        fh[((size_t)b * PHW + row * PH + col) * 256 + c] = 0;
    } else {
        int idx = (bid - 7208) * 256 + tid;    // < 524288 float4 exactly
        ((float4*)out)[idx] = make_float4(0.f, 0.f, 0.f, 0.f);
    }
}

// ---------------------------------------------------------------------------
// conv_om via single-bf16 MFMA, K-split x12; om12[kg][b][27][4096] partials.
// ---------------------------------------------------------------------------
__global__ __launch_bounds__(256) void conv_om_mfma_kernel(
    const unsigned short* __restrict__ fh,     // [2][4356][256] bf16
    const unsigned short* __restrict__ wohi,
    float* __restrict__ om12)                  // [12][2][27][4096]
{
    const int y  = blockIdx.x;     // 0..63
    const int kg = blockIdx.y;     // 0..11
    const int b  = blockIdx.z;
    const int tid = threadIdx.x;
    const int wv  = tid >> 6;
    const int lane = tid & 63;
    const int l15 = lane & 15;
    const int q   = lane >> 4;
    const int xg  = wv * 16 + l15;

    float4v acc[2];
    acc[0] = (float4v)0.0f;
    acc[1] = (float4v)0.0f;

    const unsigned short* fhb = fh + (size_t)b * PHW * 256;

#pragma unroll 3
    for (int i = 0; i < 6; ++i) {
        int kcb = kg * 6 + i;
        int k  = kcb >> 3;
        int cb = kcb & 7;
        size_t s = ((size_t)((y + k / 3) * PH + xg + k % 3)) * 256 + cb * 32 + q * 8;
        short8 bh = *(const short8*)(fhb + s);
        short8 ah0 = *(const short8*)(wohi + ((size_t)kcb * 32 + l15) * 32 + q * 8);
        short8 ah1 = *(const short8*)(wohi + ((size_t)kcb * 32 + 16 + l15) * 32 + q * 8);
        acc[0] = __builtin_amdgcn_mfma_f32_16x16x32_bf16(ah0, bh, acc[0], 0, 0, 0);
        acc[1] = __builtin_amdgcn_mfma_f32_16x16x32_bf16(ah1, bh, acc[1], 0, 0, 0);
    }

    const int p = y * 64 + xg;
    float* ob = om12 + (size_t)(kg * 2 + b) * 27 * HWPIX;
#pragma unroll
    for (int t = 0; t < 2; ++t) {
#pragma unroll
        for (int r = 0; r < 4; ++r) {
            int co = t * 16 + q * 4 + r;
            if (co < 27) ob[co * HWPIX + p] = acc[t][r];
        }
    }
}

// ---------------------------------------------------------------------------
// finalize_om: sum the 12 om partials once per (b,k,p), apply bias+sigmoid,
// and emit masked bilinear corner weights (wt4) + pre-scaled (x256) corner
// element offsets (ix4). Dedups this work across the dcn grid (was recomputed
// per cog/kg block) and takes it off dcn's critical block-startup path.
// ---------------------------------------------------------------------------
__global__ __launch_bounds__(256) void finalize_om_kernel(
    const float* __restrict__ om12,            // [12][2][27][4096]
    const float* __restrict__ bom,             // [27]
    float4* __restrict__ wt4,                  // [2][9][4096]
    int4*   __restrict__ ix4)                  // [2][9][4096]
{
    const int gid = blockIdx.x * 256 + threadIdx.x;   // < 73728
    const int p  = gid & 4095;
    const int bk = gid >> 12;                  // 0..17
    const int b  = bk / 9;
    const int k  = bk - b * 9;

    float dy = bom[2 * k], dx = bom[2 * k + 1], mm = bom[18 + k];
#pragma unroll
    for (int g = 0; g < NKG; ++g) {
        const float* ob = om12 + (size_t)(g * 2 + b) * 27 * HWPIX;
        dy += ob[(2 * k) * HWPIX + p];
        dx += ob[(2 * k + 1) * HWPIX + p];
        mm += ob[(18 + k) * HWPIX + p];
    }
    const int yy = p >> 6, xx = p & 63;
    float ys = (float)(yy - 1 + (k / 3)) + dy;
    float xs = (float)(xx - 1 + (k % 3)) + dx;
    float y0f = floorf(ys), x0f = floorf(xs);
    int y0 = (int)y0f, x0 = (int)x0f;
    float ly = ys - y0f, lx = xs - x0f;
    float m  = 1.0f / (1.0f + expf(-mm));
    bool yv0 = ((unsigned)y0 < 64u), yv1 = ((unsigned)(y0 + 1) < 64u);
    bool xv0 = ((unsigned)x0 < 64u), xv1 = ((unsigned)(x0 + 1) < 64u);
    int i00 = (y0 * 64 + x0) << 8;             // element offset * 256 ch
    float4 wt;
    int4 ix;
    wt.x = (yv0 && xv0) ? (1.0f - ly) * (1.0f - lx) * m : 0.0f;
    wt.y = (yv0 && xv1) ? (1.0f - ly) * lx * m          : 0.0f;
    wt.z = (yv1 && xv0) ? ly * (1.0f - lx) * m          : 0.0f;
    wt.w = (yv1 && xv1) ? ly * lx * m                   : 0.0f;
    ix.x = (yv0 && xv0) ? i00          : 0;
    ix.y = (yv0 && xv1) ? i00 + 256    : 0;
    ix.z = (yv1 && xv0) ? i00 + 16384  : 0;
    ix.w = (yv1 && xv1) ? i00 + 16640  : 0;
    wt4[gid] = wt;
    ix4[gid] = ix;
}

// ---------------------------------------------------------------------------
// dcn v12: 512-thread blocks (8 waves), each block computes ALL 256 co for
// its 32-px tile — the V staging (bilinear gather+interp) is done ONCE and
// feeds 2x the MFMA work of v11 (which duplicated staging across cog).
// Per-wave structure identical to v11 (acc[2][2], 144 MFMA): w = tid>>6 in
// 0..7 owns co = w*32..w*32+31. Grid (128, kg=2, b=2) = 512 blocks;
// launch_bounds(512,4) keeps the 128-VGPR cap and 16 waves/CU (2 blocks/CU,
// LDS 32.25 KB). Epilogue: fp32 atomicAdd over kg partials (pre-zeroed out).
// ---------------------------------------------------------------------------
__global__ __launch_bounds__(512, 4) void dcn_mfma_kernel(
    const unsigned short* __restrict__ xTh,    // [2][4096][256] bf16
    const float4* __restrict__ wt4,            // [2][9][4096]
    const int4* __restrict__ ix4,              // [2][9][4096]
    const unsigned short* __restrict__ whi,    // [72][256][32] bf16
    const float* __restrict__ bdcn,            // [256]
    float* __restrict__ out)                   // [2][256][4096] pre-zeroed
{
    const int tid = threadIdx.x;
    const int y   = blockIdx.x >> 1;           // 0..63
    const int xh  = blockIdx.x & 1;            // 0..1 (32-px halves)
    const int kg  = blockIdx.y;                // 0..1 (cb halves)
    const int b   = blockIdx.z;

    __shared__ float4 s_wt[288];               // masked bilinear weights
    __shared__ int4   s_ix[288];               // pre-scaled corner offsets
    __shared__ unsigned short V[288 * VSTR];   // B tiles [k*32+px][ch]

    // ---- prologue: coalesced load of precomputed weights/indices ----
    if (tid < 288) {
        int k   = tid >> 5;
        int pxl = tid & 31;
        int p   = y * 64 + xh * 32 + pxl;
        int src = ((b * 9 + k) << 12) + p;
        s_wt[tid] = wt4[src];
        s_ix[tid] = ix4[src];
    }
    __syncthreads();

    const int w    = tid >> 6;     // wave -> co base w*32
    const int lane = tid & 63;
    const int l15  = lane & 15;
    const int q    = lane >> 4;

    // staging map: cg = tid&3 (8 ch), spx = (tid>>2)&31, tapg = tid>>7 (0..3)
    const int cg   = tid & 3;
    const int spx  = (tid >> 2) & 31;
    const int tapg = tid >> 7;     // taps k = tapg + 4*j

    float4v acc[2][2];
#pragma unroll
    for (int t = 0; t < 2; ++t)
#pragma unroll
        for (int p = 0; p < 2; ++p) acc[t][p] = (float4v)0.0f;

    const unsigned short* xb = xTh + ((size_t)b << 12) * 256;

    for (int cbl = 0; cbl < 4; ++cbl) {
        const int cb = kg * 4 + cbl;

        // ---- stage: ~2.25 taps x 32 px x 8 ch per thread (16B gathers) ----
        {
            const unsigned short* xc = xb + cb * 32 + cg * 8;
#pragma unroll 3
            for (int j = 0; j < 3; ++j) {
                int k = tapg + 4 * j;
                if (k > 8) break;
                int cidx = k * 32 + spx;
                float4 wt = s_wt[cidx];
                int4   ix = s_ix[cidx];
                ushort8 u00 = *(const ushort8*)(xc + ix.x);
                ushort8 u01 = *(const ushort8*)(xc + ix.y);
                ushort8 u10 = *(const ushort8*)(xc + ix.z);
                ushort8 u11 = *(const ushort8*)(xc + ix.w);
                unsigned hv[4];
#pragma unroll
                for (int jj = 0; jj < 4; ++jj) {
                    float va = wt.x * bf2f(u00[2 * jj])     + wt.y * bf2f(u01[2 * jj])
                             + wt.z * bf2f(u10[2 * jj])     + wt.w * bf2f(u11[2 * jj]);
                    float vb = wt.x * bf2f(u00[2 * jj + 1]) + wt.y * bf2f(u01[2 * jj + 1])
                             + wt.z * bf2f(u10[2 * jj + 1]) + wt.w * bf2f(u11[2 * jj + 1]);
                    hv[jj] = (unsigned)f2bf(va) | ((unsigned)f2bf(vb) << 16);
                }
                *(uint4*)&V[cidx * VSTR + cg * 8]
                    = make_uint4(hv[0], hv[1], hv[2], hv[3]);
            }
        }
        __syncthreads();

        // ---- 9 MFMA chunks on this cb: 2 A-loads + 2 ds + 4 MFMA each ----
#pragma unroll 3
        for (int k = 0; k < 9; ++k) {
            const int kcb = k * 8 + cb;
            size_t base = ((size_t)kcb * 256 + w * 32 + l15) * 32 + q * 8;
            short8 ah0 = *(const short8*)(whi + base);
            short8 ah1 = *(const short8*)(whi + base + 16 * 32);
            short8 bh0 = *(const short8*)&V[(k * 32 + l15) * VSTR + q * 8];
            short8 bh1 = *(const short8*)&V[(k * 32 + 16 + l15) * VSTR + q * 8];
            acc[0][0] = __builtin_amdgcn_mfma_f32_16x16x32_bf16(ah0, bh0, acc[0][0], 0, 0, 0);
            acc[0][1] = __builtin_amdgcn_mfma_f32_16x16x32_bf16(ah0, bh1, acc[0][1], 0, 0, 0);
            acc[1][0] = __builtin_amdgcn_mfma_f32_16x16x32_bf16(ah1, bh0, acc[1][0], 0, 0, 0);
            acc[1][1] = __builtin_amdgcn_mfma_f32_16x16x32_bf16(ah1, bh1, acc[1][1], 0, 0, 0);
        }
        __syncthreads();
    }

    // ---- epilogue: atomic accumulate (kg partials); kg0 adds bias ----
#pragma unroll
    for (int t = 0; t < 2; ++t) {
#pragma unroll
        for (int r = 0; r < 4; ++r) {
            int co = w * 32 + t * 16 + q * 4 + r;
            float bias = (kg == 0) ? bdcn[co] : 0.0f;
#pragma unroll
            for (int p = 0; p < 2; ++p) {
                int px = xh * 32 + p * 16 + l15;
                atomicAdd(&out[(((size_t)b * COUT + co) << 12) + y * 64 + px],
                          acc[t][p][r] + bias);
            }
        }
    }
}

// ---------------------------------------------------------------------------
extern "C" void kernel_launch(void* const* d_in, const int* in_sizes, int n_in,
                              void* d_out, int out_size, void* d_ws, size_t ws_size,
                              hipStream_t stream)
{
    const float* x    = (const float*)d_in[0];
    const float* feat = (const float*)d_in[1];
    const float* wom  = (const float*)d_in[2];
    const float* bom  = (const float*)d_in[3];
    const float* wdcn = (const float*)d_in[4];
    const float* bdcn = (const float*)d_in[5];
    float* out = (float*)d_out;

    // workspace layout (all 16B-aligned)
    float* om12          = (float*)d_ws;                         // 12*2*27*4096 f32
    unsigned short* whi  = (unsigned short*)(om12 + (size_t)NKG * 2 * 27 * HWPIX);
    unsigned short* wohi = whi + (size_t)CKTOT * 256;            // 73728
    unsigned short* xTh  = wohi + 73728;                         // 2*4096*256
    unsigned short* fh   = xTh + (size_t)2 * HWPIX * 256;        // 2*4356*256
    float4* wt4          = (float4*)(fh + (size_t)2 * PHW * 256);// 2*9*4096
    int4*   ix4          = (int4*)(wt4 + (size_t)2 * 9 * HWPIX); // 2*9*4096

    prep_kernel<<<9256, 256, 0, stream>>>(x, feat, wdcn, wom, xTh, fh,
                                          whi, wohi, out);

    dim3 gco(64, NKG, 2);
    conv_om_mfma_kernel<<<gco, 256, 0, stream>>>(fh, wohi, om12);

    finalize_om_kernel<<<288, 256, 0, stream>>>(om12, bom, wt4, ix4);

    dim3 grid(128, 2, 2);
    dcn_mfma_kernel<<<grid, 512, 0, stream>>>(xTh, wt4, ix4, whi, bdcn, out);
}

// Round 2
// 127.708 us; speedup vs baseline: 1.0298x; 1.0289x over previous
//
#include <hip/hip_runtime.h>
#include <math.h>

#define BATCH 2
#define CIN   256
#define COUT  256
#define COFF  256
#define HWPIX 4096
#define CKTOT 2304
#define VSTR  40            // V row stride in shorts (80 B)
#define PH    66            // padded feat spatial dim
#define PHW   4356          // 66*66

typedef __attribute__((ext_vector_type(8))) short short8;
typedef __attribute__((ext_vector_type(8))) unsigned short ushort8;
typedef __attribute__((ext_vector_type(4))) float float4v;

__device__ __forceinline__ unsigned short f2bf(float f) {
    unsigned u = __float_as_uint(f);
    unsigned r = (u + 0x7FFFu + ((u >> 16) & 1u)) >> 16;   // RNE
    return (unsigned short)r;
}
__device__ __forceinline__ float bf2f(unsigned short h) {
    return __uint_as_float(((unsigned)h) << 16);
}

// ---------------------------------------------------------------------------
// prep: ONE kernel, blockIdx regions:
//   [0,2048)      x -> xTh (NHWC, bf16)
//   [2048,4096)   feat -> fh (NHWC, zero-padded 66x66, bf16)
//   [4096,6400)   wpack   (w_dcn -> whi, bf16, A-frag layout)
//   [6400,6688)   wpack_om(w_offset_mask -> wohi, M=32 padded, bf16)
//   [6688,7208)   zero fh borders (both batches)
//   [7208,9256)   zero out (float4) — needed by dcn's atomic epilogue
// ---------------------------------------------------------------------------
__global__ __launch_bounds__(256) void prep_kernel(
    const float* __restrict__ x, const float* __restrict__ feat,
    const float* __restrict__ wdcn, const float* __restrict__ wom,
    unsigned short* __restrict__ xTh,
    unsigned short* __restrict__ fh,
    unsigned short* __restrict__ whi,
    unsigned short* __restrict__ wohi,
    float* __restrict__ out)
{
    const int bid = blockIdx.x;
    const int tid = threadIdx.x;

    if (bid < 4096) {
        const bool isx = bid < 2048;
        const int lb = isx ? bid : bid - 2048;
        const int b  = lb >> 10;
        const int r  = lb & 1023;
        const int pt = r >> 3;       // 128 px tiles of 32
        const int ct = r & 7;        // 8 ch tiles of 32
        __shared__ float t[32][33];
        const int tx = tid & 31, ty = tid >> 5;
        const float* src = isx ? x : feat;
        const float* sb = src + ((size_t)b * 256 + ct * 32) * HWPIX + pt * 32;
#pragma unroll
        for (int i = ty; i < 32; i += 8)
            t[i][tx] = sb[(size_t)i * HWPIX + tx];
        __syncthreads();
        if (isx) {
            unsigned short* ob = xTh + ((size_t)b * HWPIX + pt * 32) * 256 + ct * 32;
#pragma unroll
            for (int i = ty; i < 32; i += 8)
                ob[(size_t)i * 256 + tx] = f2bf(t[tx][i]);
        } else {
#pragma unroll
            for (int i = ty; i < 32; i += 8) {
                int p = pt * 32 + i;
                int row = (p >> 6) + 1, col = (p & 63) + 1;
                fh[((size_t)b * PHW + row * PH + col) * 256 + ct * 32 + tx]
                    = f2bf(t[tx][i]);
            }
        }
    } else if (bid < 6400) {
        int gid = (bid - 4096) * 256 + tid;    // 0..589823
        int cc  = gid & 31;
        int co  = (gid >> 5) & 255;
        int kcb = gid >> 13;
        int k   = kcb >> 3;
        int cb  = kcb & 7;
        float w = wdcn[((size_t)co * 256 + cb * 32 + cc) * 9 + k];
        whi[gid] = f2bf(w);
    } else if (bid < 6688) {
        int gid = (bid - 6400) * 256 + tid;    // 0..73727
        int cc  = gid & 31;
        int co  = (gid >> 5) & 31;
        int kcb = gid >> 10;
        int k   = kcb >> 3;
        int cb  = kcb & 7;
        float w = 0.0f;
        if (co < 27) w = wom[(size_t)co * CKTOT + (cb * 32 + cc) * 9 + k];
        wohi[gid] = f2bf(w);
    } else if (bid < 7208) {
        int idx = (bid - 6688) * 256 + tid;    // < 133120 = 2*260*256 exactly
        int b = idx / 66560;
        int r = idx - b * 66560;
        int pidx = r >> 8;                     // 0..259 border cells
        int c = r & 255;
        int row, col;
        if (pidx < 66)       { row = 0;           col = pidx; }
        else if (pidx < 132) { row = 65;          col = pidx - 66; }
        else if (pidx < 196) { row = pidx - 131;  col = 0; }
        else                 { row = pidx - 195;  col = 65; }
        fh[((size_t)b * PHW + row * PH + col) * 256 + c] = 0;
    } else {
        int idx = (bid - 7208) * 256 + tid;    // < 524288 float4 exactly
        ((float4*)out)[idx] = make_float4(0.f, 0.f, 0.f, 0.f);
    }
}

// ---------------------------------------------------------------------------
// conv_om FUSED with finalize: each block owns 16 px x full K (2304) for one
// batch. 4 waves x 18 kcb chunks -> LDS cross-wave reduce of the 27 om
// channels -> sigmoid + masked bilinear weights + pre-scaled corner offsets
// written straight to wt4/ix4. Eliminates the om12 10.6 MB round-trip and
// the separate finalize launch. Grid (256, 2) = 512 blocks.
// ---------------------------------------------------------------------------
__global__ __launch_bounds__(256) void conv_om_fused_kernel(
    const unsigned short* __restrict__ fh,     // [2][4356][256] bf16
    const unsigned short* __restrict__ wohi,   // [72][32][32] bf16
    const float* __restrict__ bom,             // [27]
    float4* __restrict__ wt4,                  // [2][9][4096]
    int4*   __restrict__ ix4)                  // [2][9][4096]
{
    const int tile = blockIdx.x;   // 0..255 : 16-px tile
    const int b    = blockIdx.y;
    const int y    = tile >> 2;
    const int xb   = (tile & 3) * 16;
    const int tid  = threadIdx.x;
    const int wv   = tid >> 6;
    const int lane = tid & 63;
    const int l15  = lane & 15;
    const int q    = lane >> 4;

    __shared__ float red[4][32][16];

    float4v acc[2];
    acc[0] = (float4v)0.0f;
    acc[1] = (float4v)0.0f;

    const unsigned short* fhb = fh + (size_t)b * PHW * 256;

#pragma unroll 6
    for (int i = 0; i < 18; ++i) {
        int kcb = wv * 18 + i;
        int k  = kcb >> 3;
        int cb = kcb & 7;
        size_t s = ((size_t)((y + k / 3) * PH + xb + l15 + k % 3)) * 256 + cb * 32 + q * 8;
        short8 bh  = *(const short8*)(fhb + s);
        short8 ah0 = *(const short8*)(wohi + ((size_t)kcb * 32 + l15) * 32 + q * 8);
        short8 ah1 = *(const short8*)(wohi + ((size_t)kcb * 32 + 16 + l15) * 32 + q * 8);
        acc[0] = __builtin_amdgcn_mfma_f32_16x16x32_bf16(ah0, bh, acc[0], 0, 0, 0);
        acc[1] = __builtin_amdgcn_mfma_f32_16x16x32_bf16(ah1, bh, acc[1], 0, 0, 0);
    }

#pragma unroll
    for (int t = 0; t < 2; ++t)
#pragma unroll
        for (int r = 0; r < 4; ++r)
            red[wv][t * 16 + q * 4 + r][l15] = acc[t][r];
    __syncthreads();

    if (tid < 144) {
        int k   = tid >> 4;
        int pxl = tid & 15;
        float dy = bom[2 * k]     + red[0][2 * k][pxl]     + red[1][2 * k][pxl]
                                  + red[2][2 * k][pxl]     + red[3][2 * k][pxl];
        float dx = bom[2 * k + 1] + red[0][2 * k + 1][pxl] + red[1][2 * k + 1][pxl]
                                  + red[2][2 * k + 1][pxl] + red[3][2 * k + 1][pxl];
        float mm = bom[18 + k]    + red[0][18 + k][pxl]    + red[1][18 + k][pxl]
                                  + red[2][18 + k][pxl]    + red[3][18 + k][pxl];
        int xx = xb + pxl;
        float ys = (float)(y  - 1 + (k / 3)) + dy;
        float xs = (float)(xx - 1 + (k % 3)) + dx;
        float y0f = floorf(ys), x0f = floorf(xs);
        int y0 = (int)y0f, x0 = (int)x0f;
        float ly = ys - y0f, lx = xs - x0f;
        float m  = 1.0f / (1.0f + expf(-mm));
        bool yv0 = ((unsigned)y0 < 64u), yv1 = ((unsigned)(y0 + 1) < 64u);
        bool xv0 = ((unsigned)x0 < 64u), xv1 = ((unsigned)(x0 + 1) < 64u);
        int i00 = (y0 * 64 + x0) << 8;         // element offset * 256 ch
        float4 wt;
        int4 ix;
        wt.x = (yv0 && xv0) ? (1.0f - ly) * (1.0f - lx) * m : 0.0f;
        wt.y = (yv0 && xv1) ? (1.0f - ly) * lx * m          : 0.0f;
        wt.z = (yv1 && xv0) ? ly * (1.0f - lx) * m          : 0.0f;
        wt.w = (yv1 && xv1) ? ly * lx * m                   : 0.0f;
        ix.x = (yv0 && xv0) ? i00          : 0;
        ix.y = (yv0 && xv1) ? i00 + 256    : 0;
        ix.z = (yv1 && xv0) ? i00 + 16384  : 0;
        ix.w = (yv1 && xv1) ? i00 + 16640  : 0;
        int dst = ((b * 9 + k) << 12) + y * 64 + xx;
        wt4[dst] = wt;
        ix4[dst] = ix;
    }
}

// ---------------------------------------------------------------------------
// dcn v12 (unchanged from round 1): 512-thread blocks (8 waves), each block
// computes ALL 256 co for its 32-px tile; V staging done once per tile.
// Grid (128, kg=2, b=2) = 512 blocks; launch_bounds(512,4) keeps the
// 128-VGPR cap and 16 waves/CU (2 blocks/CU, LDS 32.25 KB). Epilogue:
// fp32 atomicAdd over kg partials (pre-zeroed out).
// ---------------------------------------------------------------------------
__global__ __launch_bounds__(512, 4) void dcn_mfma_kernel(
    const unsigned short* __restrict__ xTh,    // [2][4096][256] bf16
    const float4* __restrict__ wt4,            // [2][9][4096]
    const int4* __restrict__ ix4,              // [2][9][4096]
    const unsigned short* __restrict__ whi,    // [72][256][32] bf16
    const float* __restrict__ bdcn,            // [256]
    float* __restrict__ out)                   // [2][256][4096] pre-zeroed
{
    const int tid = threadIdx.x;
    const int y   = blockIdx.x >> 1;           // 0..63
    const int xh  = blockIdx.x & 1;            // 0..1 (32-px halves)
    const int kg  = blockIdx.y;                // 0..1 (cb halves)
    const int b   = blockIdx.z;

    __shared__ float4 s_wt[288];               // masked bilinear weights
    __shared__ int4   s_ix[288];               // pre-scaled corner offsets
    __shared__ unsigned short V[288 * VSTR];   // B tiles [k*32+px][ch]

    // ---- prologue: coalesced load of precomputed weights/indices ----
    if (tid < 288) {
        int k   = tid >> 5;
        int pxl = tid & 31;
        int p   = y * 64 + xh * 32 + pxl;
        int src = ((b * 9 + k) << 12) + p;
        s_wt[tid] = wt4[src];
        s_ix[tid] = ix4[src];
    }
    __syncthreads();

    const int w    = tid >> 6;     // wave -> co base w*32
    const int lane = tid & 63;
    const int l15  = lane & 15;
    const int q    = lane >> 4;

    // staging map: cg = tid&3 (8 ch), spx = (tid>>2)&31, tapg = tid>>7 (0..3)
    const int cg   = tid & 3;
    const int spx  = (tid >> 2) & 31;
    const int tapg = tid >> 7;     // taps k = tapg + 4*j

    float4v acc[2][2];
#pragma unroll
    for (int t = 0; t < 2; ++t)
#pragma unroll
        for (int p = 0; p < 2; ++p) acc[t][p] = (float4v)0.0f;

    const unsigned short* xb = xTh + ((size_t)b << 12) * 256;

    for (int cbl = 0; cbl < 4; ++cbl) {
        const int cb = kg * 4 + cbl;

        // ---- stage: ~2.25 taps x 32 px x 8 ch per thread (16B gathers) ----
        {
            const unsigned short* xc = xb + cb * 32 + cg * 8;
#pragma unroll 3
            for (int j = 0; j < 3; ++j) {
                int k = tapg + 4 * j;
                if (k > 8) break;
                int cidx = k * 32 + spx;
                float4 wt = s_wt[cidx];
                int4   ix = s_ix[cidx];
                ushort8 u00 = *(const ushort8*)(xc + ix.x);
                ushort8 u01 = *(const ushort8*)(xc + ix.y);
                ushort8 u10 = *(const ushort8*)(xc + ix.z);
                ushort8 u11 = *(const ushort8*)(xc + ix.w);
                unsigned hv[4];
#pragma unroll
                for (int jj = 0; jj < 4; ++jj) {
                    float va = wt.x * bf2f(u00[2 * jj])     + wt.y * bf2f(u01[2 * jj])
                             + wt.z * bf2f(u10[2 * jj])     + wt.w * bf2f(u11[2 * jj]);
                    float vb = wt.x * bf2f(u00[2 * jj + 1]) + wt.y * bf2f(u01[2 * jj + 1])
                             + wt.z * bf2f(u10[2 * jj + 1]) + wt.w * bf2f(u11[2 * jj + 1]);
                    hv[jj] = (unsigned)f2bf(va) | ((unsigned)f2bf(vb) << 16);
                }
                *(uint4*)&V[cidx * VSTR + cg * 8]
                    = make_uint4(hv[0], hv[1], hv[2], hv[3]);
            }
        }
        __syncthreads();

        // ---- 9 MFMA chunks on this cb: 2 A-loads + 2 ds + 4 MFMA each ----
#pragma unroll 3
        for (int k = 0; k < 9; ++k) {
            const int kcb = k * 8 + cb;
            size_t base = ((size_t)kcb * 256 + w * 32 + l15) * 32 + q * 8;
            short8 ah0 = *(const short8*)(whi + base);
            short8 ah1 = *(const short8*)(whi + base + 16 * 32);
            short8 bh0 = *(const short8*)&V[(k * 32 + l15) * VSTR + q * 8];
            short8 bh1 = *(const short8*)&V[(k * 32 + 16 + l15) * VSTR + q * 8];
            acc[0][0] = __builtin_amdgcn_mfma_f32_16x16x32_bf16(ah0, bh0, acc[0][0], 0, 0, 0);
            acc[0][1] = __builtin_amdgcn_mfma_f32_16x16x32_bf16(ah0, bh1, acc[0][1], 0, 0, 0);
            acc[1][0] = __builtin_amdgcn_mfma_f32_16x16x32_bf16(ah1, bh0, acc[1][0], 0, 0, 0);
            acc[1][1] = __builtin_amdgcn_mfma_f32_16x16x32_bf16(ah1, bh1, acc[1][1], 0, 0, 0);
        }
        __syncthreads();
    }

    // ---- epilogue: atomic accumulate (kg partials); kg0 adds bias ----
#pragma unroll
    for (int t = 0; t < 2; ++t) {
#pragma unroll
        for (int r = 0; r < 4; ++r) {
            int co = w * 32 + t * 16 + q * 4 + r;
            float bias = (kg == 0) ? bdcn[co] : 0.0f;
#pragma unroll
            for (int p = 0; p < 2; ++p) {
                int px = xh * 32 + p * 16 + l15;
                atomicAdd(&out[(((size_t)b * COUT + co) << 12) + y * 64 + px],
                          acc[t][p][r] + bias);
            }
        }
    }
}

// ---------------------------------------------------------------------------
extern "C" void kernel_launch(void* const* d_in, const int* in_sizes, int n_in,
                              void* d_out, int out_size, void* d_ws, size_t ws_size,
                              hipStream_t stream)
{
    const float* x    = (const float*)d_in[0];
    const float* feat = (const float*)d_in[1];
    const float* wom  = (const float*)d_in[2];
    const float* bom  = (const float*)d_in[3];
    const float* wdcn = (const float*)d_in[4];
    const float* bdcn = (const float*)d_in[5];
    float* out = (float*)d_out;

    // workspace layout (all 16B-aligned)
    unsigned short* whi  = (unsigned short*)d_ws;                // 589824 sh
    unsigned short* wohi = whi + (size_t)CKTOT * 256;            // 73728 sh
    unsigned short* xTh  = wohi + 73728;                         // 2*4096*256
    unsigned short* fh   = xTh + (size_t)2 * HWPIX * 256;        // 2*4356*256
    float4* wt4          = (float4*)(fh + (size_t)2 * PHW * 256);// 2*9*4096
    int4*   ix4          = (int4*)(wt4 + (size_t)2 * 9 * HWPIX); // 2*9*4096

    prep_kernel<<<9256, 256, 0, stream>>>(x, feat, wdcn, wom, xTh, fh,
                                          whi, wohi, out);

    dim3 gom(256, 2);
    conv_om_fused_kernel<<<gom, 256, 0, stream>>>(fh, wohi, bom, wt4, ix4);

    dim3 grid(128, 2, 2);
    dcn_mfma_kernel<<<grid, 512, 0, stream>>>(xTh, wt4, ix4, whi, bdcn, out);
}

// Round 3
// 124.976 us; speedup vs baseline: 1.0523x; 1.0219x over previous
//
#include <hip/hip_runtime.h>
#include <math.h>

#define BATCH 2
#define CIN   256
#define COUT  256
#define COFF  256
#define HWPIX 4096
#define CKTOT 2304
#define VSTR  40            // V row stride in shorts (80 B)
#define PH    66            // padded feat spatial dim
#define PHW   4356          // 66*66

typedef __attribute__((ext_vector_type(8))) short short8;
typedef __attribute__((ext_vector_type(8))) unsigned short ushort8;
typedef __attribute__((ext_vector_type(4))) float float4v;

__device__ __forceinline__ unsigned short f2bf(float f) {
    unsigned u = __float_as_uint(f);
    unsigned r = (u + 0x7FFFu + ((u >> 16) & 1u)) >> 16;   // RNE
    return (unsigned short)r;
}
__device__ __forceinline__ float bf2f(unsigned short h) {
    return __uint_as_float(((unsigned)h) << 16);
}

// ---------------------------------------------------------------------------
// prep: ONE kernel, blockIdx regions (out pre-zero REMOVED — dcn now does
// plain stores, no atomics):
//   [0,2048)      x -> xTh (NHWC, bf16)
//   [2048,4096)   feat -> fh (NHWC, zero-padded 66x66, bf16)
//   [4096,6400)   wpack   (w_dcn -> whi, bf16, A-frag layout)
//   [6400,6688)   wpack_om(w_offset_mask -> wohi, M=32 padded, bf16)
//   [6688,7208)   zero fh borders (both batches)
// ---------------------------------------------------------------------------
__global__ __launch_bounds__(256) void prep_kernel(
    const float* __restrict__ x, const float* __restrict__ feat,
    const float* __restrict__ wdcn, const float* __restrict__ wom,
    unsigned short* __restrict__ xTh,
    unsigned short* __restrict__ fh,
    unsigned short* __restrict__ whi,
    unsigned short* __restrict__ wohi)
{
    const int bid = blockIdx.x;
    const int tid = threadIdx.x;

    if (bid < 4096) {
        const bool isx = bid < 2048;
        const int lb = isx ? bid : bid - 2048;
        const int b  = lb >> 10;
        const int r  = lb & 1023;
        const int pt = r >> 3;       // 128 px tiles of 32
        const int ct = r & 7;        // 8 ch tiles of 32
        __shared__ float t[32][33];
        const int tx = tid & 31, ty = tid >> 5;
        const float* src = isx ? x : feat;
        const float* sb = src + ((size_t)b * 256 + ct * 32) * HWPIX + pt * 32;
#pragma unroll
        for (int i = ty; i < 32; i += 8)
            t[i][tx] = sb[(size_t)i * HWPIX + tx];
        __syncthreads();
        if (isx) {
            unsigned short* ob = xTh + ((size_t)b * HWPIX + pt * 32) * 256 + ct * 32;
#pragma unroll
            for (int i = ty; i < 32; i += 8)
                ob[(size_t)i * 256 + tx] = f2bf(t[tx][i]);
        } else {
#pragma unroll
            for (int i = ty; i < 32; i += 8) {
                int p = pt * 32 + i;
                int row = (p >> 6) + 1, col = (p & 63) + 1;
                fh[((size_t)b * PHW + row * PH + col) * 256 + ct * 32 + tx]
                    = f2bf(t[tx][i]);
            }
        }
    } else if (bid < 6400) {
        int gid = (bid - 4096) * 256 + tid;    // 0..589823
        int cc  = gid & 31;
        int co  = (gid >> 5) & 255;
        int kcb = gid >> 13;
        int k   = kcb >> 3;
        int cb  = kcb & 7;
        float w = wdcn[((size_t)co * 256 + cb * 32 + cc) * 9 + k];
        whi[gid] = f2bf(w);
    } else if (bid < 6688) {
        int gid = (bid - 6400) * 256 + tid;    // 0..73727
        int cc  = gid & 31;
        int co  = (gid >> 5) & 31;
        int kcb = gid >> 10;
        int k   = kcb >> 3;
        int cb  = kcb & 7;
        float w = 0.0f;
        if (co < 27) w = wom[(size_t)co * CKTOT + (cb * 32 + cc) * 9 + k];
        wohi[gid] = f2bf(w);
    } else {
        int idx = (bid - 6688) * 256 + tid;    // < 133120 = 2*260*256 exactly
        int b = idx / 66560;
        int r = idx - b * 66560;
        int pidx = r >> 8;                     // 0..259 border cells
        int c = r & 255;
        int row, col;
        if (pidx < 66)       { row = 0;           col = pidx; }
        else if (pidx < 132) { row = 65;          col = pidx - 66; }
        else if (pidx < 196) { row = pidx - 131;  col = 0; }
        else                 { row = pidx - 195;  col = 65; }
        fh[((size_t)b * PHW + row * PH + col) * 256 + c] = 0;
    }
}

// ---------------------------------------------------------------------------
// dcn v13: FULLY FUSED. One block = one 32-px tile, ALL 256 co, FULL K.
// Grid (128, 2) = 256 blocks (1/CU), 512 threads (8 waves).
//   Phase A: offset/mask conv for this tile in-block — 8 waves x 9 kcb
//            chunks (K-split of 2304), LDS cross-wave reduce of the 27 om
//            channels, sigmoid + masked bilinear weights + pre-scaled corner
//            offsets straight into s_wt/s_ix (no global round-trip).
//   Phase B: per cb (8 of them): bilinear-gather V into LDS, 9 MFMA chunks.
//   Epilogue: PLAIN coalesced stores (full K per block -> no atomics, no
//            pre-zeroed out).
// LDS: red 32KB + s_wt 4.5KB + s_ix 4.5KB + V 22.5KB = 63.5KB (2 blk/CU ok).
// ---------------------------------------------------------------------------
__global__ __launch_bounds__(512, 4) void dcn_fused_kernel(
    const unsigned short* __restrict__ xTh,    // [2][4096][256] bf16
    const unsigned short* __restrict__ fh,     // [2][4356][256] bf16
    const unsigned short* __restrict__ whi,    // [72][256][32] bf16
    const unsigned short* __restrict__ wohi,   // [72][32][32] bf16
    const float* __restrict__ bom,             // [27]
    const float* __restrict__ bdcn,            // [256]
    float* __restrict__ out)                   // [2][256][4096]
{
    const int tid = threadIdx.x;
    const int y   = blockIdx.x >> 1;           // 0..63
    const int xh  = blockIdx.x & 1;            // 0..1 (32-px halves)
    const int b   = blockIdx.y;

    __shared__ float red[8][32][32];           // om partials per wave
    __shared__ float4 s_wt[288];               // masked bilinear weights
    __shared__ int4   s_ix[288];               // pre-scaled corner offsets
    __shared__ unsigned short V[288 * VSTR];   // B tiles [k*32+px][ch]

    const int wv   = tid >> 6;
    const int lane = tid & 63;
    const int l15  = lane & 15;
    const int q    = lane >> 4;

    // ---- Phase A: offset/mask conv (27 x 32px), K-split across 8 waves ----
    {
        float4v aco[2][2];
#pragma unroll
        for (int t = 0; t < 2; ++t)
#pragma unroll
            for (int p = 0; p < 2; ++p) aco[t][p] = (float4v)0.0f;

        const unsigned short* fhb = fh + (size_t)b * PHW * 256;
#pragma unroll 3
        for (int i = 0; i < 9; ++i) {
            int kcb = wv * 9 + i;              // 72 kcb over 8 waves
            int k  = kcb >> 3;
            int cb = kcb & 7;
            size_t s = ((size_t)((y + k / 3) * PH + xh * 32 + (k % 3))) * 256
                     + cb * 32 + q * 8;
            short8 bh0 = *(const short8*)(fhb + s + (size_t)l15 * 256);
            short8 bh1 = *(const short8*)(fhb + s + (size_t)(16 + l15) * 256);
            short8 ah0 = *(const short8*)(wohi + ((size_t)kcb * 32 + l15) * 32 + q * 8);
            short8 ah1 = *(const short8*)(wohi + ((size_t)kcb * 32 + 16 + l15) * 32 + q * 8);
            aco[0][0] = __builtin_amdgcn_mfma_f32_16x16x32_bf16(ah0, bh0, aco[0][0], 0, 0, 0);
            aco[0][1] = __builtin_amdgcn_mfma_f32_16x16x32_bf16(ah0, bh1, aco[0][1], 0, 0, 0);
            aco[1][0] = __builtin_amdgcn_mfma_f32_16x16x32_bf16(ah1, bh0, aco[1][0], 0, 0, 0);
            aco[1][1] = __builtin_amdgcn_mfma_f32_16x16x32_bf16(ah1, bh1, aco[1][1], 0, 0, 0);
        }
#pragma unroll
        for (int t = 0; t < 2; ++t)
#pragma unroll
            for (int p = 0; p < 2; ++p)
#pragma unroll
                for (int r = 0; r < 4; ++r)
                    red[wv][t * 16 + q * 4 + r][p * 16 + l15] = aco[t][p][r];
    }
    __syncthreads();

    if (tid < 288) {
        int k   = tid >> 5;
        int pxl = tid & 31;
        float dy = bom[2 * k], dx = bom[2 * k + 1], mm = bom[18 + k];
#pragma unroll
        for (int g = 0; g < 8; ++g) {
            dy += red[g][2 * k][pxl];
            dx += red[g][2 * k + 1][pxl];
            mm += red[g][18 + k][pxl];
        }
        int xx = xh * 32 + pxl;
        float ys = (float)(y  - 1 + (k / 3)) + dy;
        float xs = (float)(xx - 1 + (k % 3)) + dx;
        float y0f = floorf(ys), x0f = floorf(xs);
        int y0 = (int)y0f, x0 = (int)x0f;
        float ly = ys - y0f, lx = xs - x0f;
        float m  = 1.0f / (1.0f + expf(-mm));
        bool yv0 = ((unsigned)y0 < 64u), yv1 = ((unsigned)(y0 + 1) < 64u);
        bool xv0 = ((unsigned)x0 < 64u), xv1 = ((unsigned)(x0 + 1) < 64u);
        int i00 = (y0 * 64 + x0) << 8;         // element offset * 256 ch
        float4 wt;
        int4 ix;
        wt.x = (yv0 && xv0) ? (1.0f - ly) * (1.0f - lx) * m : 0.0f;
        wt.y = (yv0 && xv1) ? (1.0f - ly) * lx * m          : 0.0f;
        wt.z = (yv1 && xv0) ? ly * (1.0f - lx) * m          : 0.0f;
        wt.w = (yv1 && xv1) ? ly * lx * m                   : 0.0f;
        ix.x = (yv0 && xv0) ? i00          : 0;
        ix.y = (yv0 && xv1) ? i00 + 256    : 0;
        ix.z = (yv1 && xv0) ? i00 + 16384  : 0;
        ix.w = (yv1 && xv1) ? i00 + 16640  : 0;
        s_wt[tid] = wt;                        // tid == k*32 + pxl == cidx
        s_ix[tid] = ix;
    }
    __syncthreads();

    // ---- Phase B: main DCN GEMM over all 8 cb ----
    const int w = tid >> 6;                    // wave -> co base w*32

    // staging map: cg = tid&3 (8 ch), spx = (tid>>2)&31, tapg = tid>>7 (0..3)
    const int cg   = tid & 3;
    const int spx  = (tid >> 2) & 31;
    const int tapg = tid >> 7;                 // taps k = tapg + 4*j

    float4v acc[2][2];
#pragma unroll
    for (int t = 0; t < 2; ++t)
#pragma unroll
        for (int p = 0; p < 2; ++p) acc[t][p] = (float4v)0.0f;

    const unsigned short* xb = xTh + ((size_t)b << 12) * 256;

    for (int cb = 0; cb < 8; ++cb) {
        // ---- stage: ~2.25 taps x 32 px x 8 ch per thread (16B gathers) ----
        {
            const unsigned short* xc = xb + cb * 32 + cg * 8;
#pragma unroll 3
            for (int j = 0; j < 3; ++j) {
                int k = tapg + 4 * j;
                if (k > 8) break;
                int cidx = k * 32 + spx;
                float4 wt = s_wt[cidx];
                int4   ix = s_ix[cidx];
                ushort8 u00 = *(const ushort8*)(xc + ix.x);
                ushort8 u01 = *(const ushort8*)(xc + ix.y);
                ushort8 u10 = *(const ushort8*)(xc + ix.z);
                ushort8 u11 = *(const ushort8*)(xc + ix.w);
                unsigned hv[4];
#pragma unroll
                for (int jj = 0; jj < 4; ++jj) {
                    float va = wt.x * bf2f(u00[2 * jj])     + wt.y * bf2f(u01[2 * jj])
                             + wt.z * bf2f(u10[2 * jj])     + wt.w * bf2f(u11[2 * jj]);
                    float vb = wt.x * bf2f(u00[2 * jj + 1]) + wt.y * bf2f(u01[2 * jj + 1])
                             + wt.z * bf2f(u10[2 * jj + 1]) + wt.w * bf2f(u11[2 * jj + 1]);
                    hv[jj] = (unsigned)f2bf(va) | ((unsigned)f2bf(vb) << 16);
                }
                *(uint4*)&V[cidx * VSTR + cg * 8]
                    = make_uint4(hv[0], hv[1], hv[2], hv[3]);
            }
        }
        __syncthreads();

        // ---- 9 MFMA chunks on this cb: 2 A-loads + 2 ds + 4 MFMA each ----
#pragma unroll 3
        for (int k = 0; k < 9; ++k) {
            const int kcb = k * 8 + cb;
            size_t base = ((size_t)kcb * 256 + w * 32 + l15) * 32 + q * 8;
            short8 ah0 = *(const short8*)(whi + base);
            short8 ah1 = *(const short8*)(whi + base + 16 * 32);
            short8 bh0 = *(const short8*)&V[(k * 32 + l15) * VSTR + q * 8];
            short8 bh1 = *(const short8*)&V[(k * 32 + 16 + l15) * VSTR + q * 8];
            acc[0][0] = __builtin_amdgcn_mfma_f32_16x16x32_bf16(ah0, bh0, acc[0][0], 0, 0, 0);
            acc[0][1] = __builtin_amdgcn_mfma_f32_16x16x32_bf16(ah0, bh1, acc[0][1], 0, 0, 0);
            acc[1][0] = __builtin_amdgcn_mfma_f32_16x16x32_bf16(ah1, bh0, acc[1][0], 0, 0, 0);
            acc[1][1] = __builtin_amdgcn_mfma_f32_16x16x32_bf16(ah1, bh1, acc[1][1], 0, 0, 0);
        }
        __syncthreads();
    }

    // ---- epilogue: plain stores (full K in this block) + bias ----
#pragma unroll
    for (int t = 0; t < 2; ++t) {
#pragma unroll
        for (int r = 0; r < 4; ++r) {
            int co = w * 32 + t * 16 + q * 4 + r;
            float bias = bdcn[co];
#pragma unroll
            for (int p = 0; p < 2; ++p) {
                int px = xh * 32 + p * 16 + l15;
                out[(((size_t)b * COUT + co) << 12) + y * 64 + px]
                    = acc[t][p][r] + bias;
            }
        }
    }
}

// ---------------------------------------------------------------------------
extern "C" void kernel_launch(void* const* d_in, const int* in_sizes, int n_in,
                              void* d_out, int out_size, void* d_ws, size_t ws_size,
                              hipStream_t stream)
{
    const float* x    = (const float*)d_in[0];
    const float* feat = (const float*)d_in[1];
    const float* wom  = (const float*)d_in[2];
    const float* bom  = (const float*)d_in[3];
    const float* wdcn = (const float*)d_in[4];
    const float* bdcn = (const float*)d_in[5];
    float* out = (float*)d_out;

    // workspace layout (all 16B-aligned)
    unsigned short* whi  = (unsigned short*)d_ws;                // 589824 sh
    unsigned short* wohi = whi + (size_t)CKTOT * 256;            // 73728 sh
    unsigned short* xTh  = wohi + 73728;                         // 2*4096*256
    unsigned short* fh   = xTh + (size_t)2 * HWPIX * 256;        // 2*4356*256

    prep_kernel<<<7208, 256, 0, stream>>>(x, feat, wdcn, wom, xTh, fh,
                                          whi, wohi);

    dim3 grid(128, 2);
    dcn_fused_kernel<<<grid, 512, 0, stream>>>(xTh, fh, whi, wohi,
                                               bom, bdcn, out);
}